// Round 5
// baseline (199.280 us; speedup 1.0000x reference)
//
#include <hip/hip_runtime.h>
#include <stdint.h>

typedef __attribute__((ext_vector_type(8))) short short8;
typedef __attribute__((ext_vector_type(4))) float floatx4;

__device__ inline unsigned short f2bf(float x) {
  union { float f; unsigned int u; } v; v.f = x;
  unsigned int r = v.u + 0x7FFFu + ((v.u >> 16) & 1u);  // RNE
  return (unsigned short)(r >> 16);
}

// ---------------------------------------------------------------------------
// pack_all: one dispatch does both packs. (UNCHANGED — verified)
//   blocks [0,4096):    A_bf16[4096][2048] = bf16([x | h])
//   blocks [4096,6144): Wt_perm[4096][2048] = bf16(W^T) gate-interleaved:
//                       R = (h>>5)*128 + ((h>>4)&1)*64 + g*16 + (h&15)
// ---------------------------------------------------------------------------
__global__ void pack_all(const float* __restrict__ x, const float* __restrict__ h,
                         const float* __restrict__ wi, const float* __restrict__ wh,
                         unsigned short* __restrict__ A,
                         unsigned short* __restrict__ Wt) {
  int bid = blockIdx.x;
  int t = threadIdx.x;
  if (bid < 4096) {
    int idx = bid * 256 + t;
    int row = idx >> 8;
    int kc  = (idx & 255) << 3;
    const float* src = (kc < 1024) ? (x + (size_t)row * 1024 + kc)
                                   : (h + (size_t)row * 1024 + (kc - 1024));
    float4 a = ((const float4*)src)[0];
    float4 b = ((const float4*)src)[1];
    uint4 o;
    o.x = f2bf(a.x) | ((unsigned)f2bf(a.y) << 16);
    o.y = f2bf(a.z) | ((unsigned)f2bf(a.w) << 16);
    o.z = f2bf(b.x) | ((unsigned)f2bf(b.y) << 16);
    o.w = f2bf(b.z) | ((unsigned)f2bf(b.w) << 16);
    *(uint4*)(A + (size_t)row * 2048 + kc) = o;
  } else {
    __shared__ float tile[64][65];
    int b2 = bid - 4096;
    int kt = b2 & 31;
    int nt = b2 >> 5;
    int k0 = kt << 6, n0 = nt << 6;
    const float* src = (k0 < 1024) ? (wi + (size_t)k0 * 4096)
                                   : (wh + (size_t)(k0 - 1024) * 4096);
    int c4 = (t & 15) << 2, rr = t >> 4;
#pragma unroll
    for (int p = 0; p < 4; ++p) {
      int kk = rr + p * 16;
      float4 v = *(const float4*)(src + (size_t)kk * 4096 + n0 + c4);
      tile[kk][c4 + 0] = v.x; tile[kk][c4 + 1] = v.y;
      tile[kk][c4 + 2] = v.z; tile[kk][c4 + 3] = v.w;
    }
    __syncthreads();
    int k8 = (t & 7) << 3, nn = t >> 3;
#pragma unroll
    for (int p = 0; p < 2; ++p) {
      int n = n0 + nn + p * 32;          // global N index (gate*1024 + h)
      int hh = n & 1023, g = n >> 10;
      int R = ((hh >> 5) << 7) + (((hh >> 4) & 1) << 6) + (g << 4) + (hh & 15);
      int nl = nn + p * 32;
      uint4 o;
      o.x = f2bf(tile[k8 + 0][nl]) | ((unsigned)f2bf(tile[k8 + 1][nl]) << 16);
      o.y = f2bf(tile[k8 + 2][nl]) | ((unsigned)f2bf(tile[k8 + 3][nl]) << 16);
      o.z = f2bf(tile[k8 + 4][nl]) | ((unsigned)f2bf(tile[k8 + 5][nl]) << 16);
      o.w = f2bf(tile[k8 + 6][nl]) | ((unsigned)f2bf(tile[k8 + 7][nl]) << 16);
      *(uint4*)(Wt + (size_t)R * 2048 + k0 + k8) = o;
    }
  }
}

// ---------------------------------------------------------------------------
// gemm_lstm: 256x256 8-phase, R3 = static buffers, NO order-pinning.
//   R1 failed (== old 2-phase): single LDS object + runtime offsets ->
//   compiler waitcnt pass cannot disambiguate in-flight global_load_lds
//   DMAs from phase ds_reads -> conservative vmcnt drain before every
//   phase (both pipes idle for an HBM-latency window, 4x/tile).
//   R2 failed (worse): sched_barrier(0) pinning = the documented m141
//   regression mode.
//   R3: four static __shared__ arrays + 2x-unrolled tile loop so every
//   ds_read and every DMA target is a compile-time-distinct object ->
//   compiler can prove disjointness and emit only true-dependence waits;
//   NO sched_barrier, NO blunt lgkmcnt(0) (compiler emits fine-grained
//   per-MFMA lgkmcnt, letting early waves' MFMA overlap the LDS unit
//   servicing later waves' reads). Counted vmcnt(4) once per tile.
// ---------------------------------------------------------------------------
__device__ inline void gl_lds16(const void* g, void* l) {
  __builtin_amdgcn_global_load_lds(
      (const __attribute__((address_space(1))) void*)g,
      (__attribute__((address_space(3))) void*)l, 16, 0, 0);
}

__device__ inline float sigm(float x)  { return 1.0f / (1.0f + __expf(-x)); }
__device__ inline float tanhx(float x) { return 2.0f / (1.0f + __expf(-2.0f * x)) - 1.0f; }

#define MFMA_BF16 __builtin_amdgcn_mfma_f32_16x16x32_bf16

// Stage 128 rows x 64 k (16 KiB) from SRC into DSTARR+DOFF (linear, tid*16).
#define STAGE2(SRC, DSTARR, DOFF)                                    \
  do {                                                               \
    gl_lds16((SRC) + rOff, (DSTARR) + (DOFF) + tid * 16);            \
    gl_lds16((SRC) + rOff + (size_t)64 * 4096,                       \
             (DSTARR) + (DOFF) + tid * 16 + 8192);                   \
  } while (0)

#define MFMA16(I0)                                                            \
  _Pragma("unroll")                                                           \
  for (int j = 0; j < 4; ++j) {                                               \
    acc[(I0)][j]     = MFMA_BF16(a0k0, bf[j][0], acc[(I0)][j], 0, 0, 0);      \
    acc[(I0) + 1][j] = MFMA_BF16(a1k0, bf[j][0], acc[(I0) + 1][j], 0, 0, 0);  \
  }                                                                           \
  _Pragma("unroll")                                                           \
  for (int j = 0; j < 4; ++j) {                                               \
    acc[(I0)][j]     = MFMA_BF16(a0k1, bf[j][1], acc[(I0)][j], 0, 0, 0);      \
    acc[(I0) + 1][j] = MFMA_BF16(a1k1, bf[j][1], acc[(I0) + 1][j], 0, 0, 0);  \
  }

// Phase for A-rows I0,I0+1 read from static array CA; bf[4][2] tile-resident.
// No explicit lgkmcnt: compiler inserts fine-grained waits before each MFMA.
#define PHASE(CA, I0, STAGE_STMT, TAIL_STMT)                                  \
  {                                                                           \
    const char* pa_ = (const char*)(CA) + aRowOff;                            \
    short8 a0k0 = *(const short8*)(pa_ + (I0) * 2048 + c0);                   \
    short8 a1k0 = *(const short8*)(pa_ + ((I0) + 1) * 2048 + c0);             \
    short8 a0k1 = *(const short8*)(pa_ + (I0) * 2048 + c1);                   \
    short8 a1k1 = *(const short8*)(pa_ + ((I0) + 1) * 2048 + c1);             \
    STAGE_STMT;                                                               \
    __builtin_amdgcn_s_barrier();                                             \
    __builtin_amdgcn_s_setprio(1);                                            \
    MFMA16(I0)                                                                \
    __builtin_amdgcn_s_setprio(0);                                            \
    TAIL_STMT;                                                                \
    __builtin_amdgcn_s_barrier();                                             \
  }

// Phase 0: additionally capture all 8 B-frags from static array CB.
#define PHASE0(CA, CB, STAGE_STMT)                                            \
  {                                                                           \
    const char* pb_ = (const char*)(CB) + bRowOff;                            \
    const char* pa_ = (const char*)(CA) + aRowOff;                            \
    _Pragma("unroll")                                                         \
    for (int j = 0; j < 4; ++j) {                                             \
      bf[j][0] = *(const short8*)(pb_ + j * 2048 + c0);                       \
      bf[j][1] = *(const short8*)(pb_ + j * 2048 + c1);                       \
    }                                                                         \
    short8 a0k0 = *(const short8*)(pa_ + c0);                                 \
    short8 a1k0 = *(const short8*)(pa_ + 2048 + c0);                          \
    short8 a0k1 = *(const short8*)(pa_ + c1);                                 \
    short8 a1k1 = *(const short8*)(pa_ + 2048 + c1);                          \
    STAGE_STMT;                                                               \
    __builtin_amdgcn_s_barrier();                                             \
    __builtin_amdgcn_s_setprio(1);                                            \
    MFMA16(0)                                                                 \
    __builtin_amdgcn_s_setprio(0);                                            \
    __builtin_amdgcn_s_barrier();                                             \
  }

// One K-tile: read CA/CB, stage A(next)->NA, B(next-next)->CB (same parity;
// legal: B reg-captured in ph0, two barriers before the ph2 DMA issue).
#define TILE(CA, CB, NA, AN, BN)                                              \
  {                                                                           \
    const char* aS = aBase + (size_t)(((AN) & 31) << 7);                      \
    const char* bS = bBase + (size_t)(((BN) & 31) << 7);                      \
    short8 bf[4][2];                                                          \
    PHASE0(CA, CB, STAGE2(aS, NA, 0));                                        \
    PHASE(CA, 2, STAGE2(aS + (size_t)128 * 4096, NA, 16384), );               \
    PHASE(CA, 4, STAGE2(bS, CB, 0), );                                        \
    PHASE(CA, 6, STAGE2(bS + (size_t)128 * 4096, CB, 16384),                  \
          asm volatile("s_waitcnt vmcnt(4)" ::: "memory"));                   \
  }

__global__ void __launch_bounds__(512, 2) gemm_lstm(
    const unsigned short* __restrict__ A,
    const unsigned short* __restrict__ Bt,
    const float* __restrict__ ct,
    const float* __restrict__ bi,
    const float* __restrict__ bh,
    float* __restrict__ out) {
  // Four STATIC buffers: compile-time-distinct objects for alias analysis.
  __shared__ __align__(16) char A0[32768];
  __shared__ __align__(16) char A1[32768];
  __shared__ __align__(16) char B0[32768];
  __shared__ __align__(16) char B1[32768];

  const int tid  = threadIdx.x;
  const int lane = tid & 63;
  const int wave = tid >> 6;
  const int wm = wave >> 2;        // 0..1  (M half: 128 rows)
  const int wn = wave & 3;         // 0..3  (N quarter: 64 rows)

  // ---- XCD swizzle: 256 blocks, 8 XCDs; XCD g pins bx in {2g,2g+1}. ----
  const int bid = blockIdx.x;
  const int gx = bid & 7;
  const int sx = bid >> 3;
  const int bx = (gx << 1) + (sx & 1);   // 0..15 (n block / 256)
  const int by = sx >> 1;                // 0..15 (m block / 256)
  const int m0 = by << 8;

  // ---- epilogue mapping + bias preload (gate = j, verified) ----
  const int ec = lane & 15;
  const int h  = (bx << 6) + ((wn >> 1) << 5) + ((wn & 1) << 4) + ec;
  float bias[4];
#pragma unroll
  for (int j = 0; j < 4; ++j) bias[j] = bi[j * 1024 + h] + bh[j * 1024 + h];

  // ---- staging addressing: inverse-swizzled global source, linear LDS ----
  const int sr = tid >> 3;                                  // row 0..63
  const unsigned swz = (unsigned)(((tid & 7) ^ (sr & 7)) << 4);
  const size_t rOff = (size_t)sr * 4096 + swz;
  const char* aBase = (const char*)A  + (size_t)m0 * 4096;
  const char* bBase = (const char*)Bt + (size_t)(bx << 8) * 4096;

  // ---- LDS fragment addressing (swizzled read side) ----
  const int lr  = lane & 15;
  const int kq  = lane >> 4;          // k-chunk 0..3
  const int key = lane & 7;           // == row&7 for all frag rows
  const int c0  = (kq ^ key) << 4;          // k half 0
  const int c1  = ((4 + kq) ^ key) << 4;    // k half 1
  const int aRowOff = ((wm << 7) + lr) * 128;
  const int bRowOff = ((wn << 6) + lr) * 128;

  floatx4 acc[8][4] = {};

  // ---- prologue: B(0),A(0)->buf0; B(1)->B1; vmcnt(4) lets B(1) fly. ----
  STAGE2(bBase, B0, 0);
  STAGE2(bBase + (size_t)128 * 4096, B0, 16384);
  STAGE2(aBase, A0, 0);
  STAGE2(aBase + (size_t)128 * 4096, A0, 16384);
  STAGE2(bBase + 128, B1, 0);
  STAGE2(bBase + 128 + (size_t)128 * 4096, B1, 16384);
  asm volatile("s_waitcnt vmcnt(4)" ::: "memory");
  __builtin_amdgcn_s_barrier();

  for (int it = 0; it < 16; ++it) {
    const int t = it << 1;
    TILE(A0, B0, A1, t + 1, t + 2);   // even tile t
    TILE(A1, B1, A0, t + 2, t + 3);   // odd tile t+1
  }

  // ---- fused LSTM epilogue: batch ct loads, then lane-local gates ----
  const int er = (lane >> 4) << 2;
  float cv[8][4];
#pragma unroll
  for (int i = 0; i < 8; ++i)
#pragma unroll
    for (int rg = 0; rg < 4; ++rg) {
      int row = m0 + (wm << 7) + i * 16 + er + rg;
      cv[i][rg] = ct[(size_t)row * 1024 + h];
    }
#pragma unroll
  for (int i = 0; i < 8; ++i) {
#pragma unroll
    for (int rg = 0; rg < 4; ++rg) {
      int row = m0 + (wm << 7) + i * 16 + er + rg;
      size_t o = (size_t)row * 1024 + h;
      float iv = sigm(acc[i][0][rg] + bias[0]);
      float fv = sigm(acc[i][1][rg] + bias[1]);
      float gv = tanhx(acc[i][2][rg] + bias[2]);
      float ov = sigm(acc[i][3][rg] + bias[3]);
      float cn = fv * cv[i][rg] + iv * gv;
      out[o] = ov * tanhx(cn);
      out[4194304 + o] = cn;
    }
  }
}

// ---------------------------------------------------------------------------
extern "C" void kernel_launch(void* const* d_in, const int* in_sizes, int n_in,
                              void* d_out, int out_size, void* d_ws, size_t ws_size,
                              hipStream_t stream) {
  const float* x  = (const float*)d_in[0];
  const float* ht = (const float*)d_in[1];
  const float* ct = (const float*)d_in[2];
  const float* wi = (const float*)d_in[3];
  const float* wh = (const float*)d_in[4];
  const float* bi = (const float*)d_in[5];
  const float* bh = (const float*)d_in[6];
  float* out = (float*)d_out;

  char* ws = (char*)d_ws;
  unsigned short* Abf = (unsigned short*)ws;                 // 16 MiB
  unsigned short* Wbf = (unsigned short*)(ws + (16u << 20)); // 16 MiB

  pack_all<<<6144, 256, 0, stream>>>(x, ht, wi, wh, Abf, Wbf);
  gemm_lstm<<<256, 512, 0, stream>>>(Abf, Wbf, ct, bi, bh, out);
}

// Round 6
// 195.191 us; speedup vs baseline: 1.0209x; 1.0209x over previous
//
#include <hip/hip_runtime.h>
#include <stdint.h>

typedef __attribute__((ext_vector_type(8))) short short8;
typedef __attribute__((ext_vector_type(4))) float floatx4;

__device__ inline unsigned short f2bf(float x) {
  union { float f; unsigned int u; } v; v.f = x;
  unsigned int r = v.u + 0x7FFFu + ((v.u >> 16) & 1u);  // RNE
  return (unsigned short)(r >> 16);
}

// ---------------------------------------------------------------------------
// pack_all: one dispatch does both packs. (UNCHANGED — verified)
//   blocks [0,4096):    A_bf16[4096][2048] = bf16([x | h])
//   blocks [4096,6144): Wt_perm[4096][2048] = bf16(W^T) gate-interleaved:
//                       R = (h>>5)*128 + ((h>>4)&1)*64 + g*16 + (h&15)
// ---------------------------------------------------------------------------
__global__ void pack_all(const float* __restrict__ x, const float* __restrict__ h,
                         const float* __restrict__ wi, const float* __restrict__ wh,
                         unsigned short* __restrict__ A,
                         unsigned short* __restrict__ Wt) {
  int bid = blockIdx.x;
  int t = threadIdx.x;
  if (bid < 4096) {
    int idx = bid * 256 + t;
    int row = idx >> 8;
    int kc  = (idx & 255) << 3;
    const float* src = (kc < 1024) ? (x + (size_t)row * 1024 + kc)
                                   : (h + (size_t)row * 1024 + (kc - 1024));
    float4 a = ((const float4*)src)[0];
    float4 b = ((const float4*)src)[1];
    uint4 o;
    o.x = f2bf(a.x) | ((unsigned)f2bf(a.y) << 16);
    o.y = f2bf(a.z) | ((unsigned)f2bf(a.w) << 16);
    o.z = f2bf(b.x) | ((unsigned)f2bf(b.y) << 16);
    o.w = f2bf(b.z) | ((unsigned)f2bf(b.w) << 16);
    *(uint4*)(A + (size_t)row * 2048 + kc) = o;
  } else {
    __shared__ float tile[64][65];
    int b2 = bid - 4096;
    int kt = b2 & 31;
    int nt = b2 >> 5;
    int k0 = kt << 6, n0 = nt << 6;
    const float* src = (k0 < 1024) ? (wi + (size_t)k0 * 4096)
                                   : (wh + (size_t)(k0 - 1024) * 4096);
    int c4 = (t & 15) << 2, rr = t >> 4;
#pragma unroll
    for (int p = 0; p < 4; ++p) {
      int kk = rr + p * 16;
      float4 v = *(const float4*)(src + (size_t)kk * 4096 + n0 + c4);
      tile[kk][c4 + 0] = v.x; tile[kk][c4 + 1] = v.y;
      tile[kk][c4 + 2] = v.z; tile[kk][c4 + 3] = v.w;
    }
    __syncthreads();
    int k8 = (t & 7) << 3, nn = t >> 3;
#pragma unroll
    for (int p = 0; p < 2; ++p) {
      int n = n0 + nn + p * 32;          // global N index (gate*1024 + h)
      int hh = n & 1023, g = n >> 10;
      int R = ((hh >> 5) << 7) + (((hh >> 4) & 1) << 6) + (g << 4) + (hh & 15);
      int nl = nn + p * 32;
      uint4 o;
      o.x = f2bf(tile[k8 + 0][nl]) | ((unsigned)f2bf(tile[k8 + 1][nl]) << 16);
      o.y = f2bf(tile[k8 + 2][nl]) | ((unsigned)f2bf(tile[k8 + 3][nl]) << 16);
      o.z = f2bf(tile[k8 + 4][nl]) | ((unsigned)f2bf(tile[k8 + 5][nl]) << 16);
      o.w = f2bf(tile[k8 + 6][nl]) | ((unsigned)f2bf(tile[k8 + 7][nl]) << 16);
      *(uint4*)(Wt + (size_t)R * 2048 + k0 + k8) = o;
    }
  }
}

// ---------------------------------------------------------------------------
// gemm_lstm R6: drain-proof software-pipelined phases.
//   Measured R0/R1/R2/R5 all ~1426 cyc/phase = 576 (LDS svc) + 620 (MFMA)
//   serial: hipcc's lgkmcnt(0)-drain before every s_barrier forces all
//   waves' reads complete before any wave passes -> no read/MFMA overlap.
//   Fix: per phase [bar; issue reads for NEXT consumption; issue stage;
//   counted lgkmcnt -> frags issued LAST phase are ready; MFMA]. Reads are
//   always serviced under the previous MFMA window and never cross >1
//   barrier, so the barrier drain costs ~0 even if emitted.
//   Phases: ph0 rows0-3(x)k0 [PAIN/PBIN prefetched], reads B@k1+A0-3@k1;
//           ph1 rows0-3(x)k1, reads A4-7@k0;
//           ph2 rows4-7(x)k0, reads A4-7@k1; vmcnt(2) tail (all waves'
//               A(t+1)/B(t+1) DMAs landed before ph3 barrier);
//           ph3 rows4-7(x)k1, prefetches next-tile B@k0+A0-3@k0.
//   Staging: ph0/ph1 A(t+1)->NA; ph2/ph3 B(t+2)->CB (same parity; legal:
//   all B reads of CB complete before ph2 barrier). 1 barrier/phase.
// ---------------------------------------------------------------------------
__device__ inline void gl_lds16(const void* g, void* l) {
  __builtin_amdgcn_global_load_lds(
      (const __attribute__((address_space(1))) void*)g,
      (__attribute__((address_space(3))) void*)l, 16, 0, 0);
}

__device__ inline float sigm(float x)  { return 1.0f / (1.0f + __expf(-x)); }
__device__ inline float tanhx(float x) { return 2.0f / (1.0f + __expf(-2.0f * x)) - 1.0f; }

#define MFMA_BF16 __builtin_amdgcn_mfma_f32_16x16x32_bf16

// Stage 128 rows x 64 k (16 KiB) from SRC into DSTARR+DOFF (linear, tid*16).
#define STAGE2(SRC, DSTARR, DOFF)                                    \
  do {                                                               \
    gl_lds16((SRC) + rOff, (DSTARR) + (DOFF) + tid * 16);            \
    gl_lds16((SRC) + rOff + (size_t)64 * 4096,                       \
             (DSTARR) + (DOFF) + tid * 16 + 8192);                   \
  } while (0)

#define TILE(CA, CB, NA, NB, PBIN, PAIN, PBOUT, PAOUT, AN, BN)                \
  {                                                                           \
    const char* aS = aBase + (size_t)(((AN) & 31) << 7);                      \
    const char* bS = bBase + (size_t)(((BN) & 31) << 7);                      \
    const char* pa_ = (const char*)(CA) + aRowOff;                            \
    const char* pb_ = (const char*)(CB) + bRowOff;                            \
    short8 bk1[4], a1f[4], a2f[4], a3f[4];                                    \
    /* ph0: MFMA rows0-3 x k0 (prefetched); issue k1 reads (8) */             \
    __builtin_amdgcn_s_barrier();                                             \
    _Pragma("unroll")                                                         \
    for (int j = 0; j < 4; ++j) bk1[j] = *(const short8*)(pb_ + j * 2048 + c1); \
    _Pragma("unroll")                                                         \
    for (int i = 0; i < 4; ++i) a1f[i] = *(const short8*)(pa_ + i * 2048 + c1); \
    STAGE2(aS, NA, 0);                                                        \
    asm volatile("s_waitcnt lgkmcnt(8)" ::: "memory");                        \
    __builtin_amdgcn_s_setprio(1);                                            \
    _Pragma("unroll")                                                         \
    for (int i = 0; i < 4; ++i)                                               \
      _Pragma("unroll")                                                       \
      for (int j = 0; j < 4; ++j)                                             \
        acc[i][j] = MFMA_BF16(PAIN[i], PBIN[j], acc[i][j], 0, 0, 0);          \
    __builtin_amdgcn_s_setprio(0);                                            \
    /* ph1: MFMA rows0-3 x k1; issue A4-7@k0 (4) */                           \
    __builtin_amdgcn_s_barrier();                                             \
    _Pragma("unroll")                                                         \
    for (int i = 0; i < 4; ++i) a2f[i] = *(const short8*)(pa_ + (4 + i) * 2048 + c0); \
    STAGE2(aS + (size_t)128 * 4096, NA, 16384);                               \
    asm volatile("s_waitcnt lgkmcnt(4)" ::: "memory");                        \
    __builtin_amdgcn_s_setprio(1);                                            \
    _Pragma("unroll")                                                         \
    for (int i = 0; i < 4; ++i)                                               \
      _Pragma("unroll")                                                       \
      for (int j = 0; j < 4; ++j)                                             \
        acc[i][j] = MFMA_BF16(a1f[i], bk1[j], acc[i][j], 0, 0, 0);            \
    __builtin_amdgcn_s_setprio(0);                                            \
    /* ph2: MFMA rows4-7 x k0; issue A4-7@k1 (4); vmcnt(2) tail */            \
    __builtin_amdgcn_s_barrier();                                             \
    _Pragma("unroll")                                                         \
    for (int i = 0; i < 4; ++i) a3f[i] = *(const short8*)(pa_ + (4 + i) * 2048 + c1); \
    STAGE2(bS, CB, 0);                                                        \
    asm volatile("s_waitcnt lgkmcnt(4)" ::: "memory");                        \
    __builtin_amdgcn_s_setprio(1);                                            \
    _Pragma("unroll")                                                         \
    for (int i = 0; i < 4; ++i)                                               \
      _Pragma("unroll")                                                       \
      for (int j = 0; j < 4; ++j)                                             \
        acc[4 + i][j] = MFMA_BF16(a2f[i], PBIN[j], acc[4 + i][j], 0, 0, 0);   \
    __builtin_amdgcn_s_setprio(0);                                            \
    asm volatile("s_waitcnt vmcnt(2)" ::: "memory");                          \
    /* ph3: MFMA rows4-7 x k1; prefetch next-tile ph0 frags (8) */            \
    __builtin_amdgcn_s_barrier();                                             \
    {                                                                         \
      const char* na_ = (const char*)(NA) + aRowOff;                          \
      const char* nb_ = (const char*)(NB) + bRowOff;                          \
      _Pragma("unroll")                                                       \
      for (int j = 0; j < 4; ++j) PBOUT[j] = *(const short8*)(nb_ + j * 2048 + c0); \
      _Pragma("unroll")                                                       \
      for (int i = 0; i < 4; ++i) PAOUT[i] = *(const short8*)(na_ + i * 2048 + c0); \
    }                                                                         \
    STAGE2(bS + (size_t)128 * 4096, CB, 16384);                               \
    asm volatile("s_waitcnt lgkmcnt(8)" ::: "memory");                        \
    __builtin_amdgcn_s_setprio(1);                                            \
    _Pragma("unroll")                                                         \
    for (int i = 0; i < 4; ++i)                                               \
      _Pragma("unroll")                                                       \
      for (int j = 0; j < 4; ++j)                                             \
        acc[4 + i][j] = MFMA_BF16(a3f[i], bk1[j], acc[4 + i][j], 0, 0, 0);    \
    __builtin_amdgcn_s_setprio(0);                                            \
  }

__global__ void __launch_bounds__(512, 2) gemm_lstm(
    const unsigned short* __restrict__ A,
    const unsigned short* __restrict__ Bt,
    const float* __restrict__ ct,
    const float* __restrict__ bi,
    const float* __restrict__ bh,
    float* __restrict__ out) {
  __shared__ __align__(16) char A0[32768];
  __shared__ __align__(16) char A1[32768];
  __shared__ __align__(16) char B0[32768];
  __shared__ __align__(16) char B1[32768];

  const int tid  = threadIdx.x;
  const int lane = tid & 63;
  const int wave = tid >> 6;
  const int wm = wave >> 2;        // 0..1  (M half: 128 rows)
  const int wn = wave & 3;         // 0..3  (N quarter: 64 rows)

  // ---- XCD swizzle: 256 blocks, 8 XCDs; XCD g pins bx in {2g,2g+1}. ----
  const int bid = blockIdx.x;
  const int gx = bid & 7;
  const int sx = bid >> 3;
  const int bx = (gx << 1) + (sx & 1);   // 0..15 (n block / 256)
  const int by = sx >> 1;                // 0..15 (m block / 256)
  const int m0 = by << 8;

  // ---- epilogue mapping + bias preload (gate = j, verified) ----
  const int ec = lane & 15;
  const int h  = (bx << 6) + ((wn >> 1) << 5) + ((wn & 1) << 4) + ec;
  float bias[4];
#pragma unroll
  for (int j = 0; j < 4; ++j) bias[j] = bi[j * 1024 + h] + bh[j * 1024 + h];

  // ---- staging addressing: inverse-swizzled global source, linear LDS ----
  const int sr = tid >> 3;                                  // row 0..63
  const unsigned swz = (unsigned)(((tid & 7) ^ (sr & 7)) << 4);
  const size_t rOff = (size_t)sr * 4096 + swz;
  const char* aBase = (const char*)A  + (size_t)m0 * 4096;
  const char* bBase = (const char*)Bt + (size_t)(bx << 8) * 4096;

  // ---- LDS fragment addressing (swizzled read side) ----
  const int lr  = lane & 15;
  const int kq  = lane >> 4;          // k-chunk 0..3
  const int key = lane & 7;           // == row&7 for all frag rows
  const int c0  = (kq ^ key) << 4;          // k half 0
  const int c1  = ((4 + kq) ^ key) << 4;    // k half 1
  const int aRowOff = ((wm << 7) + lr) * 128;
  const int bRowOff = ((wn << 6) + lr) * 128;

  floatx4 acc[8][4] = {};
  short8 pb0[4], pa0[4], pb1[4], pa1[4];   // loop-carried prefetched ph0 frags

  // ---- prologue: B(0)->B0, A(0)->A0, B(1)->B1; vmcnt(4) -> tile0 data
  //      landed (B(1) in flight); barrier; prefetch tile0 ph0 frags. ----
  STAGE2(bBase, B0, 0);
  STAGE2(bBase + (size_t)128 * 4096, B0, 16384);
  STAGE2(aBase, A0, 0);
  STAGE2(aBase + (size_t)128 * 4096, A0, 16384);
  STAGE2(bBase + 128, B1, 0);
  STAGE2(bBase + 128 + (size_t)128 * 4096, B1, 16384);
  asm volatile("s_waitcnt vmcnt(4)" ::: "memory");
  __builtin_amdgcn_s_barrier();
  {
    const char* pbp = (const char*)B0 + bRowOff;
    const char* pap = (const char*)A0 + aRowOff;
#pragma unroll
    for (int j = 0; j < 4; ++j) pb0[j] = *(const short8*)(pbp + j * 2048 + c0);
#pragma unroll
    for (int i = 0; i < 4; ++i) pa0[i] = *(const short8*)(pap + i * 2048 + c0);
  }

  for (int it = 0; it < 16; ++it) {
    const int t = it << 1;
    TILE(A0, B0, A1, B1, pb0, pa0, pb1, pa1, t + 1, t + 2);   // even tile
    TILE(A1, B1, A0, B0, pb1, pa1, pb0, pa0, t + 2, t + 3);   // odd tile
  }

  // ---- fused LSTM epilogue: batch ct loads, then lane-local gates ----
  const int er = (lane >> 4) << 2;
  float cv[8][4];
#pragma unroll
  for (int i = 0; i < 8; ++i)
#pragma unroll
    for (int rg = 0; rg < 4; ++rg) {
      int row = m0 + (wm << 7) + i * 16 + er + rg;
      cv[i][rg] = ct[(size_t)row * 1024 + h];
    }
#pragma unroll
  for (int i = 0; i < 8; ++i) {
#pragma unroll
    for (int rg = 0; rg < 4; ++rg) {
      int row = m0 + (wm << 7) + i * 16 + er + rg;
      size_t o = (size_t)row * 1024 + h;
      float iv = sigm(acc[i][0][rg] + bias[0]);
      float fv = sigm(acc[i][1][rg] + bias[1]);
      float gv = tanhx(acc[i][2][rg] + bias[2]);
      float ov = sigm(acc[i][3][rg] + bias[3]);
      float cn = fv * cv[i][rg] + iv * gv;
      out[o] = ov * tanhx(cn);
      out[4194304 + o] = cn;
    }
  }
}

// ---------------------------------------------------------------------------
extern "C" void kernel_launch(void* const* d_in, const int* in_sizes, int n_in,
                              void* d_out, int out_size, void* d_ws, size_t ws_size,
                              hipStream_t stream) {
  const float* x  = (const float*)d_in[0];
  const float* ht = (const float*)d_in[1];
  const float* ct = (const float*)d_in[2];
  const float* wi = (const float*)d_in[3];
  const float* wh = (const float*)d_in[4];
  const float* bi = (const float*)d_in[5];
  const float* bh = (const float*)d_in[6];
  float* out = (float*)d_out;

  char* ws = (char*)d_ws;
  unsigned short* Abf = (unsigned short*)ws;                 // 16 MiB
  unsigned short* Wbf = (unsigned short*)(ws + (16u << 20)); // 16 MiB

  pack_all<<<6144, 256, 0, stream>>>(x, ht, wi, wh, Abf, Wbf);
  gemm_lstm<<<256, 512, 0, stream>>>(Abf, Wbf, ct, bi, bh, out);
}

// Round 7
// 194.172 us; speedup vs baseline: 1.0263x; 1.0052x over previous
//
#include <hip/hip_runtime.h>
#include <stdint.h>

typedef __attribute__((ext_vector_type(8))) short short8;
typedef __attribute__((ext_vector_type(4))) float floatx4;

__device__ inline unsigned short f2bf(float x) {
  union { float f; unsigned int u; } v; v.f = x;
  unsigned int r = v.u + 0x7FFFu + ((v.u >> 16) & 1u);  // RNE
  return (unsigned short)(r >> 16);
}

// ---------------------------------------------------------------------------
// pack_all: one dispatch does both packs. (UNCHANGED — verified)
//   blocks [0,4096):    A_bf16[4096][2048] = bf16([x | h])
//   blocks [4096,6144): Wt_perm[4096][2048] = bf16(W^T) gate-interleaved:
//                       R = (h>>5)*128 + ((h>>4)&1)*64 + g*16 + (h&15)
// ---------------------------------------------------------------------------
__global__ void pack_all(const float* __restrict__ x, const float* __restrict__ h,
                         const float* __restrict__ wi, const float* __restrict__ wh,
                         unsigned short* __restrict__ A,
                         unsigned short* __restrict__ Wt) {
  int bid = blockIdx.x;
  int t = threadIdx.x;
  if (bid < 4096) {
    int idx = bid * 256 + t;
    int row = idx >> 8;
    int kc  = (idx & 255) << 3;
    const float* src = (kc < 1024) ? (x + (size_t)row * 1024 + kc)
                                   : (h + (size_t)row * 1024 + (kc - 1024));
    float4 a = ((const float4*)src)[0];
    float4 b = ((const float4*)src)[1];
    uint4 o;
    o.x = f2bf(a.x) | ((unsigned)f2bf(a.y) << 16);
    o.y = f2bf(a.z) | ((unsigned)f2bf(a.w) << 16);
    o.z = f2bf(b.x) | ((unsigned)f2bf(b.y) << 16);
    o.w = f2bf(b.z) | ((unsigned)f2bf(b.w) << 16);
    *(uint4*)(A + (size_t)row * 2048 + kc) = o;
  } else {
    __shared__ float tile[64][65];
    int b2 = bid - 4096;
    int kt = b2 & 31;
    int nt = b2 >> 5;
    int k0 = kt << 6, n0 = nt << 6;
    const float* src = (k0 < 1024) ? (wi + (size_t)k0 * 4096)
                                   : (wh + (size_t)(k0 - 1024) * 4096);
    int c4 = (t & 15) << 2, rr = t >> 4;
#pragma unroll
    for (int p = 0; p < 4; ++p) {
      int kk = rr + p * 16;
      float4 v = *(const float4*)(src + (size_t)kk * 4096 + n0 + c4);
      tile[kk][c4 + 0] = v.x; tile[kk][c4 + 1] = v.y;
      tile[kk][c4 + 2] = v.z; tile[kk][c4 + 3] = v.w;
    }
    __syncthreads();
    int k8 = (t & 7) << 3, nn = t >> 3;
#pragma unroll
    for (int p = 0; p < 2; ++p) {
      int n = n0 + nn + p * 32;          // global N index (gate*1024 + h)
      int hh = n & 1023, g = n >> 10;
      int R = ((hh >> 5) << 7) + (((hh >> 4) & 1) << 6) + (g << 4) + (hh & 15);
      int nl = nn + p * 32;
      uint4 o;
      o.x = f2bf(tile[k8 + 0][nl]) | ((unsigned)f2bf(tile[k8 + 1][nl]) << 16);
      o.y = f2bf(tile[k8 + 2][nl]) | ((unsigned)f2bf(tile[k8 + 3][nl]) << 16);
      o.z = f2bf(tile[k8 + 4][nl]) | ((unsigned)f2bf(tile[k8 + 5][nl]) << 16);
      o.w = f2bf(tile[k8 + 6][nl]) | ((unsigned)f2bf(tile[k8 + 7][nl]) << 16);
      *(uint4*)(Wt + (size_t)R * 2048 + k0 + k8) = o;
    }
  }
}

// ---------------------------------------------------------------------------
// gemm_lstm R7: R0 structure (best measured: 76.9-77.5 us, MfmaUtil 39%)
// with ONE change: __launch_bounds__(256,3) -> (256,4).
//   Evidence: five schedule variants (R0/R1/R2/R5/R6) all land 76-85 us ->
//   intra-block scheduling is not the lever. R0's OccupancyPercent=30.5%
//   (9.8 waves/CU vs 12 theoretical) reveals a ragged dispatch tail:
//   1024 blocks at 3/CU = epoch of 768 + straggler epoch of 256 blocks at
//   1 block/CU. Resources (60 VGPR + 64 AGPR = 124/wave; 32 KB LDS) fit
//   4 blocks/CU: 1024 blocks = exactly 4/CU -> one clean epoch, 16 waves/CU,
//   4 independent barrier groups per CU for implicit staging/MFMA overlap
//   (m114 mechanism — the only thing that produced the best MfmaUtil).
// ---------------------------------------------------------------------------
__device__ inline void gl_lds16(const void* g, void* l) {
  __builtin_amdgcn_global_load_lds(
      (const __attribute__((address_space(1))) void*)g,
      (__attribute__((address_space(3))) void*)l, 16, 0, 0);
}

__device__ inline float sigm(float x)  { return 1.0f / (1.0f + __expf(-x)); }
__device__ inline float tanhx(float x) { return 2.0f / (1.0f + __expf(-2.0f * x)) - 1.0f; }

__global__ void __launch_bounds__(256, 4) gemm_lstm(
    const unsigned short* __restrict__ A,
    const unsigned short* __restrict__ Bt,
    const float* __restrict__ ct,
    const float* __restrict__ bi,
    const float* __restrict__ bh,
    float* __restrict__ out) {
  constexpr int K = 2048;
  __shared__ char AsB[128 * 128];  // 128 rows x 64 bf16 (128 B)
  __shared__ char BsB[128 * 128];
  const int tid  = threadIdx.x;
  const int lane = tid & 63;
  const int wave = tid >> 6;
  const int wm = wave >> 1, wn = wave & 1;

  // ---- XCD supertile swizzle (bijection on [0,1024)) ----
  // g = id%8 -> XCD band; s = id/8; bx = g*4 + (s&3); by = (s>>4)*4 + ((s>>2)&3)
  const int bid = blockIdx.x;
  const int g  = bid & 7;
  const int s  = bid >> 3;
  const int bx = (g << 2) + (s & 3);
  const int by = ((s >> 4) << 2) + ((s >> 2) & 3);
  const int m0 = by << 7;
  const int n0 = bx << 7;   // linear row block in permuted W
  const int h0 = bx << 5;   // 32 h per block

  // epilogue lane mapping + bias preload (latency hidden by K-loop)
  const int er = (lane >> 4) << 2;
  const int ec = lane & 15;
  const int h  = h0 + (wn << 4) + ec;
  float bias[4];
#pragma unroll
  for (int j = 0; j < 4; ++j) bias[j] = bi[j * 1024 + h] + bh[j * 1024 + h];

  // ---- staging: uniform base (SGPR) + ONE shared per-lane offset ----
  const int sr = tid >> 3;                              // LDS row 0..31 (+p*32)
  const int cs = ((tid & 7) ^ (sr & 7)) << 4;           // XOR-swizzled source chunk
  const unsigned voff = (unsigned)sr * 4096u + (unsigned)cs;  // per-lane, invariant
  const char* aBase = (const char*)A  + (size_t)m0 * 4096;    // row = 4096 B
  const char* bBase = (const char*)Bt + (size_t)n0 * 4096;
  char* aD = AsB + tid * 16;
  char* bD = BsB + tid * 16;

  floatx4 acc[4][4] = {};
  // LDS fragment bases (loop-invariant; f*16 rows -> +f*2048 immediate)
  const int rA = (wm << 6) + (lane & 15);
  const int rB = (wn << 6) + (lane & 15);
  const int keyc = lane & 7;
  const int kq   = lane >> 4;
  const char* aF0 = AsB + rA * 128 + ((kq ^ keyc) << 4);
  const char* aF1 = AsB + rA * 128 + (((4 + kq) ^ keyc) << 4);
  const char* bF0 = BsB + rB * 128 + ((kq ^ keyc) << 4);
  const char* bF1 = BsB + rB * 128 + (((4 + kq) ^ keyc) << 4);

  for (int ks = 0; ks < K; ks += 64) {
    const char* aIt = aBase + ks * 2;   // uniform
    const char* bIt = bBase + ks * 2;   // uniform
#pragma unroll
    for (int p = 0; p < 4; ++p) gl_lds16(aIt + p * 131072 + voff, aD + p * 4096);
#pragma unroll
    for (int p = 0; p < 4; ++p) gl_lds16(bIt + p * 131072 + voff, bD + p * 4096);
    __syncthreads();
    {
      short8 af[4], bfr[4];
#pragma unroll
      for (int f = 0; f < 4; ++f) {
        af[f]  = *(const short8*)(aF0 + f * 2048);
        bfr[f] = *(const short8*)(bF0 + f * 2048);
      }
#pragma unroll
      for (int i = 0; i < 4; ++i)
#pragma unroll
        for (int j = 0; j < 4; ++j)
          acc[i][j] = __builtin_amdgcn_mfma_f32_16x16x32_bf16(af[i], bfr[j], acc[i][j], 0, 0, 0);
    }
    {
      short8 af[4], bfr[4];
#pragma unroll
      for (int f = 0; f < 4; ++f) {
        af[f]  = *(const short8*)(aF1 + f * 2048);
        bfr[f] = *(const short8*)(bF1 + f * 2048);
      }
#pragma unroll
      for (int i = 0; i < 4; ++i)
#pragma unroll
        for (int j = 0; j < 4; ++j)
          acc[i][j] = __builtin_amdgcn_mfma_f32_16x16x32_bf16(af[i], bfr[j], acc[i][j], 0, 0, 0);
    }
    __syncthreads();
  }

  // ---- fused LSTM epilogue: batch ct loads (one overlapped miss window),
  // then lane-local gates (j == gate) ----
  float cv[4][4];
#pragma unroll
  for (int i = 0; i < 4; ++i)
#pragma unroll
    for (int rg = 0; rg < 4; ++rg) {
      int row = m0 + (wm << 6) + i * 16 + er + rg;
      cv[i][rg] = ct[(size_t)row * 1024 + h];
    }
#pragma unroll
  for (int i = 0; i < 4; ++i) {
#pragma unroll
    for (int rg = 0; rg < 4; ++rg) {
      int row = m0 + (wm << 6) + i * 16 + er + rg;
      size_t o = (size_t)row * 1024 + h;
      float iv = sigm(acc[i][0][rg] + bias[0]);
      float fv = sigm(acc[i][1][rg] + bias[1]);
      float gv = tanhx(acc[i][2][rg] + bias[2]);
      float ov = sigm(acc[i][3][rg] + bias[3]);
      float cn = fv * cv[i][rg] + iv * gv;
      out[o] = ov * tanhx(cn);
      out[4194304 + o] = cn;
    }
  }
}

// ---------------------------------------------------------------------------
extern "C" void kernel_launch(void* const* d_in, const int* in_sizes, int n_in,
                              void* d_out, int out_size, void* d_ws, size_t ws_size,
                              hipStream_t stream) {
  const float* x  = (const float*)d_in[0];
  const float* ht = (const float*)d_in[1];
  const float* ct = (const float*)d_in[2];
  const float* wi = (const float*)d_in[3];
  const float* wh = (const float*)d_in[4];
  const float* bi = (const float*)d_in[5];
  const float* bh = (const float*)d_in[6];
  float* out = (float*)d_out;

  char* ws = (char*)d_ws;
  unsigned short* Abf = (unsigned short*)ws;                 // 16 MiB
  unsigned short* Wbf = (unsigned short*)(ws + (16u << 20)); // 16 MiB

  pack_all<<<6144, 256, 0, stream>>>(x, ht, wi, wh, Abf, Wbf);
  gemm_lstm<<<1024, 256, 0, stream>>>(Abf, Wbf, ct, bi, bh, out);
}